// Round 1
// 3559.185 us; speedup vs baseline: 2.7377x; 2.7377x over previous
//
#include <hip/hip_runtime.h>

#define T_ 100
#define B_ 256
#define N_ 512
#define BN (B_ * N_)
#define TBN ((size_t)T_ * BN)

typedef short s16x8 __attribute__((ext_vector_type(8)));
typedef float f32x4 __attribute__((ext_vector_type(4)));
typedef unsigned short u16;
typedef unsigned short u16x4 __attribute__((ext_vector_type(4)));

__device__ __forceinline__ float bf2f(u16 u) {
  union { unsigned int i; float f; } v; v.i = ((unsigned int)u) << 16; return v.f;
}
__device__ __forceinline__ u16 f2bf(float f) {
  union { float f; unsigned int i; } v; v.f = f;
  unsigned int x = v.i;
  return (u16)((x + 0x7fffu + ((x >> 16) & 1u)) >> 16);
}

struct P {
  // fp32 inputs
  const float *v, *p0, *encW, *encb, *Win, *bin, *tauMin, *tauAin;
  const float *Wd, *bd, *Wr, *br, *tauMr, *tauAr, *Wout, *bout, *tauMo;
  // workspace
  u16 *spin[2];      // input-layer spikes (bf16 {0,1}), parity buffered
  u16 *spr[3][2];    // recurrent-layer spikes, parity buffered
  float *memin[2], *adin[2];  // input-layer state (parity)
  float *memr;       // [3][B*N]  enc-init handoff for L-blocks
  float *memout;     // [B*N]     enc-init handoff for RO-blocks
  float *cst;  // [0,512) a_in | [512,1024) ro_in | [1024,2560) a_rnn |
               // [2560,4096) ro_rnn | [4096,4608) a_out
  unsigned int *flags;  // [5][T_][2] monotonic counters, zeroed per run
  float *out;
};

// ---- cross-block sync helpers (device-scope; XCD L2s are not coherent) ----
__device__ __forceinline__ unsigned ldflag(unsigned int* f) {
  return __hip_atomic_load(f, __ATOMIC_RELAXED, __HIP_MEMORY_SCOPE_AGENT);
}
__device__ __forceinline__ void waitge(unsigned int* f, unsigned tgt) {
  while (ldflag(f) < tgt) __builtin_amdgcn_s_sleep(2);
}
// flag index: stage s (0=IN,1=L0,2=L1,3=L2,4=RO), timestep t, row-slab rb
__device__ __forceinline__ unsigned int* FLG(const P& p, int s, int t, int rb) {
  return p.flags + (s * T_ + t) * 2 + rb;
}

// One 16x16 row-tile x 16-col GEMM over K=512 against 3 LDS-resident bf16
// split planes (regions lds0, lds0+16K, lds0+32K). A streamed from global.
// Accumulation order matches the previous (passing) kernel exactly.
__device__ __forceinline__ void gemm_tile(const u16* A, int arow, const char* lds0,
                                          int lrow, int quad, f32x4& a0, f32x4& a1,
                                          f32x4& a2) {
  s16x8 af[16];
  const u16* Ar = A + (size_t)arow * 512 + quad * 8;
#pragma unroll
  for (int kb = 0; kb < 16; ++kb) af[kb] = *(const s16x8*)(Ar + kb * 32);
  const int base = (lrow << 10) + (quad << 4);
  const int swz = (lrow & 7) << 4;
#pragma unroll
  for (int kb = 0; kb < 16; ++kb) {
    const int bo = (base + kb * 64) ^ swz;  // XOR-swizzle: conflict-free ds_read_b128
    a0 = __builtin_amdgcn_mfma_f32_16x16x32_bf16(af[kb], *(const s16x8*)(lds0 + bo), a0, 0, 0, 0);
    a1 = __builtin_amdgcn_mfma_f32_16x16x32_bf16(af[kb], *(const s16x8*)(lds0 + 16384 + bo), a1, 0, 0, 0);
    a2 = __builtin_amdgcn_mfma_f32_16x16x32_bf16(af[kb], *(const s16x8*)(lds0 + 32768 + bo), a2, 0, 0, 0);
  }
}

// Persistent kernel: whole T-loop, pipelined stages, flag-synced.
// Grid = 240 blocks x 256 threads, 96 KB dynamic LDS => 1 block/CU => all
// blocks co-resident on 256 CUs => spin-sync cannot deadlock.
//   bid [0,192): recurrent layer l=bid>>6, rb=(bid>>5)&1 (128-row slab), cc=bid&31 (16 cols)
//   bid [192,224): readout, rb, 32-col chunk
//   bid [224,240): input-layer ALIF, 16 rows each
__global__ __launch_bounds__(256, 1) void k_persist(P p) {
  extern __shared__ __align__(16) char lds[];
  const int bid = blockIdx.x;
  const int tid = threadIdx.x;
  const int wave = tid >> 6, lane = tid & 63;
  const int lrow = lane & 15, quad = lane >> 4;

  if (bid < 192) {
    // ================= recurrent layer blocks =================
    const int l = bid >> 6;
    const int rb = (bid >> 5) & 1;
    const int cc = bid & 31;
    // --- split Wd[l],Wr[l] col-slice into 6 LDS regions (hi/mid/lo each) ---
    for (int e = tid; e < 8192; e += 256) {
      const int j = e >> 9, k = e & 511;
      const int byte = ((j << 10) + (k << 1)) ^ ((j & 7) << 4);
      {
        float w = p.Wd[((size_t)(l * 512 + cc * 16 + j)) * 512 + k];
        u16 h = f2bf(w); float r1 = w - bf2f(h);
        u16 m = f2bf(r1); float r2 = r1 - bf2f(m);
        *(u16*)(lds + 0 * 16384 + byte) = h;
        *(u16*)(lds + 1 * 16384 + byte) = m;
        *(u16*)(lds + 2 * 16384 + byte) = f2bf(r2);
      }
      {
        float w = p.Wr[((size_t)(l * 512 + cc * 16 + j)) * 512 + k];
        u16 h = f2bf(w); float r1 = w - bf2f(h);
        u16 m = f2bf(r1); float r2 = r1 - bf2f(m);
        *(u16*)(lds + 3 * 16384 + byte) = h;
        *(u16*)(lds + 4 * 16384 + byte) = m;
        *(u16*)(lds + 5 * 16384 + byte) = f2bf(r2);
      }
    }
    const int n = cc * 16 + lrow;
    const float alpha = p.cst[1024 + l * 512 + n];
    const float ro    = p.cst[2560 + l * 512 + n];
    const float bias  = p.bd[l * 512 + n] + p.br[l * 512 + n];
    // ALIF state in registers: 2 row-tiles x 4 rows per thread
    float mem[2][4], ad[2][4], spk[2][4];
#pragma unroll
    for (int ti = 0; ti < 2; ++ti)
#pragma unroll
      for (int i = 0; i < 4; ++i) {
        const int b = rb * 128 + (wave * 2 + ti) * 16 + quad * 4 + i;
        mem[ti][i] = p.memr[l * BN + b * 512 + n];
        ad[ti][i] = 0.01f;
        spk[ti][i] = 0.f;
      }
    __syncthreads();
    const unsigned tprev = (l == 0) ? 8u : 32u;
    const unsigned tnext = (l == 2) ? 16u : 32u;
    for (int t = 0; t < T_; ++t) {
      const int pw = t & 1, pr = pw ^ 1;
      if (tid == 0) {
        waitge(FLG(p, l, t, rb), tprev);                      // feed-forward input ready
        if (t >= 1) waitge(FLG(p, 1 + l, t - 1, rb), 32u);    // own layer t-1 published
        if (t >= 2) waitge(FLG(p, 2 + l, t - 2, rb), tnext);  // pw buffer consumed
        __threadfence();  // acquire
      }
      __syncthreads();
      const u16* Aff  = (l == 0) ? p.spin[pw] : p.spr[l - 1][pw];
      const u16* Arec = p.spr[l][pr];
      u16* spc = p.spr[l][pw];
      float* outm = p.out + (size_t)(3 + 2 * l) * TBN + (size_t)t * BN;
      float* outs = p.out + (size_t)(4 + 2 * l) * TBN + (size_t)t * BN;
#pragma unroll
      for (int ti = 0; ti < 2; ++ti) {
        const int rowbase = rb * 128 + (wave * 2 + ti) * 16;
        f32x4 a0 = {0.f, 0.f, 0.f, 0.f}, a1 = a0, a2 = a0;
        gemm_tile(Aff,  rowbase + lrow, lds,             lrow, quad, a0, a1, a2);
        gemm_tile(Arec, rowbase + lrow, lds + 3 * 16384, lrow, quad, a0, a1, a2);
#pragma unroll
        for (int i = 0; i < 4; ++i) {
          const int b = rowbase + quad * 4 + i;
          const int idx = b * 512 + n;
          const float acc = (a0[i] + a1[i]) + a2[i];
          float adv = ad[ti][i], mv = mem[ti][i], sv = spk[ti][i];
          adv = ro * adv + (1.f - ro) * sv;
          const float Bth = 0.01f + 1.8f * adv;
          mv = mv * alpha + (1.f - alpha) * (acc + bias) - Bth * sv;
          const float ns = (mv - Bth) > 0.f ? 1.f : 0.f;
          mem[ti][i] = mv; ad[ti][i] = adv; spk[ti][i] = ns;
          spc[idx] = (ns != 0.f) ? (u16)0x3F80 : (u16)0;
          outm[idx] = mv;
          outs[idx] = ns;
        }
      }
      __syncthreads();
      if (tid == 0) { __threadfence(); atomicAdd(FLG(p, 1 + l, t, rb), 1u); }  // release
    }
  } else if (bid < 224) {
    // ================= readout blocks =================
    const int rr = bid - 192;
    const int rb = rr >> 4, c32 = rr & 15;
    for (int e = tid; e < 16384; e += 256) {
      const int j = e >> 9, k = e & 511;
      float w = p.Wout[((size_t)(c32 * 32 + j)) * 512 + k];
      u16 h = f2bf(w); float r1 = w - bf2f(h);
      u16 m = f2bf(r1); float r2 = r1 - bf2f(m);
      char* base = lds + ((j >> 4) * 3) * 16384;
      const int jl = j & 15;
      const int byte = ((jl << 10) + (k << 1)) ^ ((jl & 7) << 4);
      *(u16*)(base + byte) = h;
      *(u16*)(base + 16384 + byte) = m;
      *(u16*)(base + 32768 + byte) = f2bf(r2);
    }
    const int ch = wave & 1, tg = wave >> 1;
    const int n = c32 * 32 + ch * 16 + lrow;
    const float ao = p.cst[4096 + n];
    const float bo = p.bout[n];
    float mo[4][4];
#pragma unroll
    for (int pi = 0; pi < 4; ++pi)
#pragma unroll
      for (int i = 0; i < 4; ++i) {
        const int b = rb * 128 + (tg * 4 + pi) * 16 + quad * 4 + i;
        mo[pi][i] = p.memout[b * 512 + n];
      }
    __syncthreads();
    for (int t = 0; t < T_; ++t) {
      const int pw = t & 1;
      if (tid == 0) { waitge(FLG(p, 3, t, rb), 32u); __threadfence(); }
      __syncthreads();
      const u16* A = p.spr[2][pw];
      const char* lds0 = lds + (ch * 3) * 16384;
#pragma unroll
      for (int pi = 0; pi < 4; ++pi) {
        const int rowbase = rb * 128 + (tg * 4 + pi) * 16;
        f32x4 a0 = {0.f, 0.f, 0.f, 0.f}, a1 = a0, a2 = a0;
        gemm_tile(A, rowbase + lrow, lds0, lrow, quad, a0, a1, a2);
#pragma unroll
        for (int i = 0; i < 4; ++i) {
          const int b = rowbase + quad * 4 + i;
          const int idx = b * 512 + n;
          const float dot = (a0[i] + a1[i]) + a2[i];
          float mv = mo[pi][i];
          mv = mv * ao + (1.f - ao) * (dot + bo);
          mo[pi][i] = mv;
          const float g = mv > 0.f ? mv : 0.f;
          p.out[(size_t)t * BN + idx] = g;
          p.out[9 * TBN + (size_t)t * BN + idx] = g;
        }
      }
      __syncthreads();
      if (tid == 0) { __threadfence(); atomicAdd(FLG(p, 4, t, rb), 1u); }
    }
  } else {
    // ================= input-layer ALIF blocks =================
    const int g = bid - 224;       // 16 rows each
    const int rbi = g >> 3;
    for (int t = 0; t < T_; ++t) {
      const int pw = t & 1, pr = pw ^ 1;
      if (tid == 0 && t >= 2) waitge(FLG(p, 1, t - 2, rbi), 32u);  // spin[pw] consumed
      __syncthreads();
#pragma unroll
      for (int pass = 0; pass < 8; ++pass) {
        const int e4 = tid + pass * 256;        // [0, 2048): groups of 4 neurons
        const int rl = e4 >> 7, nn = (e4 & 127) << 2;
        const int b = g * 16 + rl;
        const int idx = b * 512 + nn;
        const float v0 = p.v[(t * 256 + b) * 2 + 0];
        const float v1 = p.v[(t * 256 + b) * 2 + 1];
        f32x4 mv = *(const f32x4*)(p.memin[pr] + idx);
        f32x4 av = *(const f32x4*)(p.adin[pr] + idx);
        u16x4 sv = *(const u16x4*)(p.spin[pr] + idx);
        f32x4 al = *(const f32x4*)(p.cst + nn);
        f32x4 rv = *(const f32x4*)(p.cst + 512 + nn);
        f32x4 bi = *(const f32x4*)(p.bin + nn);
        f32x4 w0 = *(const f32x4*)(p.Win + nn * 2);
        f32x4 w1 = *(const f32x4*)(p.Win + nn * 2 + 4);
        f32x4 om, os;
        u16x4 sb;
#pragma unroll
        for (int i = 0; i < 4; ++i) {
          const float wi0 = (i == 0) ? w0[0] : (i == 1) ? w0[2] : (i == 2) ? w1[0] : w1[2];
          const float wi1 = (i == 0) ? w0[1] : (i == 1) ? w0[3] : (i == 2) ? w1[1] : w1[3];
          const float inp = v0 * wi0 + v1 * wi1 + bi[i];
          const float sk = bf2f(sv[i]);
          float adv = av[i], m = mv[i];
          adv = rv[i] * adv + (1.f - rv[i]) * sk;
          const float Bth = 0.01f + 1.8f * adv;
          m = m * al[i] + (1.f - al[i]) * inp - Bth * sk;
          const float ns = (m - Bth) > 0.f ? 1.f : 0.f;
          mv[i] = m; av[i] = adv; om[i] = m; os[i] = ns;
          sb[i] = (ns != 0.f) ? (u16)0x3F80 : (u16)0;
        }
        *(f32x4*)(p.memin[pw] + idx) = mv;
        *(f32x4*)(p.adin[pw] + idx) = av;
        *(u16x4*)(p.spin[pw] + idx) = sb;
        *(f32x4*)(p.out + 1 * TBN + (size_t)t * BN + idx) = om;
        *(f32x4*)(p.out + 2 * TBN + (size_t)t * BN + idx) = os;
      }
      __syncthreads();
      if (tid == 0) { __threadfence(); atomicAdd(FLG(p, 0, t, rbi), 1u); }
    }
  }
}

__global__ void k_init_misc(P p) {
  const int stride = gridDim.x * blockDim.x;
  const int i0 = blockIdx.x * blockDim.x + threadIdx.x;
  for (int i = i0; i < 512; i += stride) {
    p.cst[i]        = expf(-1.f / p.tauMin[i]);
    p.cst[512 + i]  = expf(-1.f / p.tauAin[i]);
    p.cst[4096 + i] = expf(-1.f / p.tauMo[i]);
  }
  for (int i = i0; i < 1536; i += stride) {
    p.cst[1024 + i] = expf(-1.f / p.tauMr[i]);
    p.cst[2560 + i] = expf(-1.f / p.tauAr[i]);
  }
  for (int i = i0; i < BN; i += stride) {
    p.spin[1][i] = 0;
    p.spr[0][1][i] = 0;
    p.spr[1][1][i] = 0;
    p.spr[2][1][i] = 0;
    p.adin[1][i] = 0.01f;
  }
  for (int i = i0; i < 5 * T_ * 2; i += stride) p.flags[i] = 0;
}

// Membrane init from place-code encoders (fp32 VALU) — unchanged math.
__global__ __launch_bounds__(128) void k_init_enc(P p) {
  const int wg = blockIdx.x, rb = wg >> 5, cc = wg & 31;
  for (int a = threadIdx.x; a < 2560; a += 128) {
    const int l = a >> 9, rem = a & 511;
    const int b = rb * 32 + (rem >> 4), n = cc * 16 + (rem & 15);
    const float* ap = p.p0 + b * 512;
    const float* wp = p.encW + ((size_t)(l * 512 + n)) * 512;
    float acc = 0.f;
    for (int k = 0; k < 512; ++k) acc += (ap[k] * 1000.0f) * wp[k];
    const float x = acc + p.encb[l * 512 + n];
    const float val = 0.015f * (1.f / (1.f + expf(-x)));
    const int idx = b * 512 + n;
    if (l == 0)      p.memin[1][idx] = val;
    else if (l <= 3) p.memr[(l - 1) * BN + idx] = val;
    else             p.memout[idx] = val;
  }
}

extern "C" void kernel_launch(void* const* d_in, const int* in_sizes, int n_in,
                              void* d_out, int out_size, void* d_ws, size_t ws_size,
                              hipStream_t stream) {
  P p;
  p.v      = (const float*)d_in[0];
  p.p0     = (const float*)d_in[1];
  p.encW   = (const float*)d_in[2];
  p.encb   = (const float*)d_in[3];
  p.Win    = (const float*)d_in[4];
  p.bin    = (const float*)d_in[5];
  p.tauMin = (const float*)d_in[6];
  p.tauAin = (const float*)d_in[7];
  p.Wd     = (const float*)d_in[8];
  p.bd     = (const float*)d_in[9];
  p.Wr     = (const float*)d_in[10];
  p.br     = (const float*)d_in[11];
  p.tauMr  = (const float*)d_in[12];
  p.tauAr  = (const float*)d_in[13];
  p.Wout   = (const float*)d_in[14];
  p.bout   = (const float*)d_in[15];
  p.tauMo  = (const float*)d_in[16];
  p.out    = (float*)d_out;

  char* w = (char*)d_ws;
  size_t off = 0;
  auto carve = [&](size_t bytes) -> void* {
    void* r = (void*)(w + off);
    off += (bytes + 255) & ~(size_t)255;
    return r;
  };
  for (int q = 0; q < 2; ++q) p.spin[q] = (u16*)carve((size_t)BN * 2);
  for (int l = 0; l < 3; ++l)
    for (int q = 0; q < 2; ++q) p.spr[l][q] = (u16*)carve((size_t)BN * 2);
  for (int q = 0; q < 2; ++q) p.memin[q] = (float*)carve((size_t)BN * 4);
  for (int q = 0; q < 2; ++q) p.adin[q] = (float*)carve((size_t)BN * 4);
  p.memr   = (float*)carve((size_t)3 * BN * 4);
  p.memout = (float*)carve((size_t)BN * 4);
  p.cst    = (float*)carve((size_t)4608 * 4);
  p.flags  = (unsigned int*)carve((size_t)5 * T_ * 2 * 4);

  // 96 KB dynamic LDS opt-in (host-side attribute; legal under graph capture).
  (void)hipFuncSetAttribute((const void*)k_persist,
                            hipFuncAttributeMaxDynamicSharedMemorySize, 98304);

  hipLaunchKernelGGL(k_init_misc, dim3(256), dim3(256), 0, stream, p);
  hipLaunchKernelGGL(k_init_enc, dim3(256), dim3(128), 0, stream, p);
  hipLaunchKernelGGL(k_persist, dim3(240), dim3(256), 98304, stream, p);
}